// Round 5
// baseline (1010.489 us; speedup 1.0000x reference)
//
#include <hip/hip_runtime.h>
#include <hip/hip_bf16.h>

#define B_  2
#define N_  512
#define M_  512
#define H_  256
#define NH_ 8
#define DH_ 32

typedef __attribute__((ext_vector_type(4))) float f32x4;
typedef __attribute__((ext_vector_type(8))) short bf16x8;

static __device__ __forceinline__ float fast_exp2(float x) { return __builtin_amdgcn_exp2f(x); }
static __device__ __forceinline__ float fast_rcp(float x)  { return __builtin_amdgcn_rcpf(x); }

// fp32 -> bf16 bits, round-to-nearest-even (inputs are finite)
static __device__ __forceinline__ unsigned short f2b(float f) {
    unsigned int u = __float_as_uint(f);
    u += 0x7fffu + ((u >> 16) & 1u);
    return (unsigned short)(u >> 16);
}

// ---------------------------------------------------------------------------
// K1: fused input projections. blockIdx.y selects {q@Wq, k@Wk, k@Wv}.
// ---------------------------------------------------------------------------
#define TM 8
__global__ __launch_bounds__(256) void proj3_kernel(const float* __restrict__ Q,
                                                    const float* __restrict__ K,
                                                    const float* __restrict__ Wq,
                                                    const float* __restrict__ Wk,
                                                    const float* __restrict__ Wv,
                                                    float* __restrict__ qp,
                                                    float* __restrict__ kp,
                                                    float* __restrict__ vv) {
    const int which = blockIdx.y;
    const float* X = (which == 0) ? Q : K;
    const float* W = (which == 0) ? Wq : (which == 1) ? Wk : Wv;
    float* Y = (which == 0) ? qp : (which == 1) ? kp : vv;

    __shared__ __align__(16) float xs[TM][H_];
    const int t = threadIdx.x;
    const int r0 = blockIdx.x * TM;
    for (int idx = t; idx < TM * H_; idx += 256)
        xs[idx >> 8][idx & 255] = X[(size_t)(r0 + (idx >> 8)) * H_ + (idx & 255)];
    __syncthreads();

    float acc[TM];
#pragma unroll
    for (int r = 0; r < TM; ++r) acc[r] = 0.f;

    const float* wrow = W + (size_t)t * H_;
    for (int k = 0; k < H_; k += 4) {
        float4 w4 = *(const float4*)(wrow + k);
#pragma unroll
        for (int r = 0; r < TM; ++r) {
            acc[r] += w4.x * xs[r][k] + w4.y * xs[r][k + 1] +
                      w4.z * xs[r][k + 2] + w4.w * xs[r][k + 3];
        }
    }
#pragma unroll
    for (int r = 0; r < TM; ++r) Y[(size_t)(r0 + r) * H_ + t] = acc[r];
}

// single-projection variant for the output GEMM
__global__ __launch_bounds__(256) void proj_kernel(const float* __restrict__ X,
                                                   const float* __restrict__ W,
                                                   float* __restrict__ Y) {
    __shared__ __align__(16) float xs[TM][H_];
    const int t = threadIdx.x;
    const int r0 = blockIdx.x * TM;
    for (int idx = t; idx < TM * H_; idx += 256)
        xs[idx >> 8][idx & 255] = X[(size_t)(r0 + (idx >> 8)) * H_ + (idx & 255)];
    __syncthreads();

    float acc[TM];
#pragma unroll
    for (int r = 0; r < TM; ++r) acc[r] = 0.f;

    const float* wrow = W + (size_t)t * H_;
    for (int k = 0; k < H_; k += 4) {
        float4 w4 = *(const float4*)(wrow + k);
#pragma unroll
        for (int r = 0; r < TM; ++r) {
            acc[r] += w4.x * xs[r][k] + w4.y * xs[r][k + 1] +
                      w4.z * xs[r][k + 2] + w4.w * xs[r][k + 3];
        }
    }
#pragma unroll
    for (int r = 0; r < TM; ++r) Y[(size_t)(r0 + r) * H_ + t] = acc[r];
}

// ---------------------------------------------------------------------------
// K3: multi-head dot-product attention (flash-style over j-tiles of 128)
// ---------------------------------------------------------------------------
__global__ __launch_bounds__(256) void mh_attn_kernel(const float* __restrict__ qp,
                                                      const float* __restrict__ kp,
                                                      const float* __restrict__ vv,
                                                      float* __restrict__ ctx) {
    __shared__ __align__(16) float ks[128][36];
    __shared__ __align__(16) float vs[128][36];
    const int t = threadIdx.x;
    const int bh = blockIdx.x;
    const int b = bh >> 3, head = bh & 7;
    const int i0 = blockIdx.y * 32;
    const int r = t >> 3, sub = t & 7;
    const int i = i0 + r;
    const float rs = 0.17677669529663687f;   // 1/sqrt(32)
    const float C = 1.4426950408889634f;     // log2(e)

    const float* qptr = qp + ((size_t)(b * N_ + i)) * H_ + head * DH_;
    float4 q[8];
#pragma unroll
    for (int d = 0; d < 8; ++d) q[d] = *(const float4*)(qptr + d * 4);

    float mrun = -1e30f, lrun = 0.f;
    float4 o[8];
#pragma unroll
    for (int d = 0; d < 8; ++d) o[d] = make_float4(0.f, 0.f, 0.f, 0.f);

    for (int jt = 0; jt < 4; ++jt) {
        __syncthreads();
#pragma unroll
        for (int cc = 0; cc < 4; ++cc) {
            int cIdx = t + cc * 256;
            int jr = cIdx >> 3, d4 = cIdx & 7;
            size_t gofs = ((size_t)(b * M_ + jt * 128 + jr)) * H_ + head * DH_ + d4 * 4;
            *(float4*)(&ks[jr][d4 * 4]) = *(const float4*)(kp + gofs);
            *(float4*)(&vs[jr][d4 * 4]) = *(const float4*)(vv + gofs);
        }
        __syncthreads();

        float s16[16];
#pragma unroll
        for (int jj = 0; jj < 16; ++jj) {
            const float* kr = ks[sub + jj * 8];
            float a = 0.f;
#pragma unroll
            for (int d = 0; d < 8; ++d) {
                float4 kv = *(const float4*)(kr + d * 4);
                a += q[d].x * kv.x + q[d].y * kv.y + q[d].z * kv.z + q[d].w * kv.w;
            }
            s16[jj] = a * rs;
        }
        float tm = s16[0];
#pragma unroll
        for (int jj = 1; jj < 16; ++jj) tm = fmaxf(tm, s16[jj]);
        float mnew = fmaxf(mrun, tm);
        float corr = fast_exp2((mrun - mnew) * C);
        lrun *= corr;
#pragma unroll
        for (int d = 0; d < 8; ++d) {
            o[d].x *= corr; o[d].y *= corr; o[d].z *= corr; o[d].w *= corr;
        }
        mrun = mnew;
#pragma unroll
        for (int jj = 0; jj < 16; ++jj) {
            float p = fast_exp2((s16[jj] - mrun) * C);
            lrun += p;
            const float* vr = vs[sub + jj * 8];
#pragma unroll
            for (int d = 0; d < 8; ++d) {
                float4 vx = *(const float4*)(vr + d * 4);
                o[d].x = __builtin_fmaf(p, vx.x, o[d].x);
                o[d].y = __builtin_fmaf(p, vx.y, o[d].y);
                o[d].z = __builtin_fmaf(p, vx.z, o[d].z);
                o[d].w = __builtin_fmaf(p, vx.w, o[d].w);
            }
        }
    }

#pragma unroll
    for (int mask = 1; mask < 8; mask <<= 1) {
        float om = __shfl_xor(mrun, mask, 64);
        float ol = __shfl_xor(lrun, mask, 64);
        float Mx = fmaxf(mrun, om);
        float fa = fast_exp2((mrun - Mx) * C);
        float fb = fast_exp2((om - Mx) * C);
        lrun = lrun * fa + ol * fb;
#pragma unroll
        for (int d = 0; d < 8; ++d) {
            float ox = __shfl_xor(o[d].x, mask, 64);
            float oy = __shfl_xor(o[d].y, mask, 64);
            float oz = __shfl_xor(o[d].z, mask, 64);
            float ow = __shfl_xor(o[d].w, mask, 64);
            o[d].x = o[d].x * fa + ox * fb;
            o[d].y = o[d].y * fa + oy * fb;
            o[d].z = o[d].z * fa + oz * fb;
            o[d].w = o[d].w * fa + ow * fb;
        }
        mrun = Mx;
    }
    float inv = fast_rcp(lrun);
    float4 r4 = make_float4(0.f, 0.f, 0.f, 0.f);
#pragma unroll
    for (int d = 0; d < 8; ++d) if (sub == d) r4 = o[d];
    r4.x *= inv; r4.y *= inv; r4.z *= inv; r4.w *= inv;
    *(float4*)(ctx + ((size_t)(b * N_ + i)) * H_ + head * DH_ + sub * 4) = r4;
}

// ---------------------------------------------------------------------------
// K2: additive-attention branch.
// XCD-locality schedule: xcd=bid&7 owns (b,i) idx in [xcd*128, xcd*128+128);
// its 32 blocks (slot=bid>>3) process idx = xcd*128 + it*32 + slot, so all
// blocks of an XCD stream the SAME 256-KB kp j-block concurrently -> L2 hits.
// qrow staged in LDS pre-scaled by 2*log2(e); 2-deep kp register prefetch;
// chunked col map o=(c>>2)*64+li*4+(c&3) -> 256B-contiguous nt stores.
// ---------------------------------------------------------------------------
#define K2_BLOCKS 256

__global__ __launch_bounds__(512, 2) void addattn_kernel(const float* __restrict__ qp,
                                                         const float* __restrict__ kp,
                                                         const float* __restrict__ Wv,
                                                         float* __restrict__ attn) {
    __shared__ __align__(16) unsigned short wv_s[H_ * H_];  // 128 KB swizzled bf16
    __shared__ __align__(16) float qrow[H_];                // 1 KB, pre-scaled

    const int t = threadIdx.x;
    const int lane = t & 63;
    const int w = t >> 6;        // wave 0..7
    const int li = lane & 15;
    const int kq = lane >> 4;    // 0..3
    const int wrow0 = w * 32;
    const float C = 1.4426950408889634f;
    const float L2E2 = 2.885390081777927f;   // 2*log2(e)

    // ---- stage Wv as bf16; 16B-slot XOR swizzle keyed on (o>>2)&15 ----
#pragma unroll
    for (int itr = 0; itr < 16; ++itr) {
        int sIdx = t + itr * 512;          // 16B-slot index 0..8191
        int o = sIdx >> 5;
        int slot = sIdx & 31;
        const float* src = Wv + (size_t)o * H_ + slot * 8;
        float4 a = *(const float4*)(src);
        float4 bq = *(const float4*)(src + 4);
        union { unsigned short us[8]; uint4 v; } pk;
        pk.us[0] = f2b(a.x);  pk.us[1] = f2b(a.y);  pk.us[2] = f2b(a.z);  pk.us[3] = f2b(a.w);
        pk.us[4] = f2b(bq.x); pk.us[5] = f2b(bq.y); pk.us[6] = f2b(bq.z); pk.us[7] = f2b(bq.w);
        int dslot = slot ^ ((o >> 2) & 15);
        *(uint4*)(wv_s + (size_t)o * 256 + dslot * 8) = pk.v;
    }

    const int xcd  = blockIdx.x & 7;
    const int slot = blockIdx.x >> 3;

    float4 cur[2][2], nxtA[2][2], nxtB[2][2];

    // helper: load kp 32B slices for (rowbase, kk) into dst
#define LDK(rowbase, kkv, dst)                                                     \
    {                                                                              \
        _Pragma("unroll")                                                          \
        for (int rf = 0; rf < 2; ++rf) {                                           \
            const float* kr_ = kp + ((size_t)((rowbase) + wrow0 + rf * 16 + li)) * H_ \
                               + (kkv) * 32 + kq * 8;                              \
            dst[rf][0] = *(const float4*)(kr_);                                    \
            dst[rf][1] = *(const float4*)(kr_ + 4);                                \
        }                                                                          \
    }

    // prologue: prefetch first j-block's kk=0,1
    {
        const int idx0 = xcd * 128 + slot;
        const int b0 = idx0 >> 9;
        LDK(b0 * M_, 0, cur);
        LDK(b0 * M_, 1, nxtA);
    }

    for (int it = 0; it < 4; ++it) {
        const int idx = xcd * 128 + it * 32 + slot;
        const int b = idx >> 9;
        const int i = idx & (N_ - 1);

        __syncthreads();   // prior iter done with qrow
        if (t < 64) {
            f32x4 qv = *(const f32x4*)(qp + ((size_t)(b * N_ + i)) * H_ + t * 4);
            qv *= L2E2;
            *(f32x4*)(qrow + t * 4) = qv;
        }
        __syncthreads();   // qrow (and, on it=0, wv_s) visible

        for (int jb = 0; jb < 2; ++jb) {
            const int j0 = jb << 8;
            const int rowbase = b * M_ + j0;

            f32x4 acc[2][16];
#pragma unroll
            for (int rf = 0; rf < 2; ++rf)
#pragma unroll
                for (int c = 0; c < 16; ++c) acc[rf][c] = (f32x4){0.f, 0.f, 0.f, 0.f};

#pragma unroll
            for (int kk = 0; kk < 8; ++kk) {
                if (kk < 6) LDK(rowbase, kk + 2, nxtB);

                f32x4 qs0 = *(const f32x4*)(qrow + kk * 32 + kq * 8);
                f32x4 qs1 = *(const f32x4*)(qrow + kk * 32 + kq * 8 + 4);

                bf16x8 afr[2];
#pragma unroll
                for (int rf = 0; rf < 2; ++rf) {
                    float xin[8] = {
                        __builtin_fmaf(cur[rf][0].x, L2E2, qs0[0]),
                        __builtin_fmaf(cur[rf][0].y, L2E2, qs0[1]),
                        __builtin_fmaf(cur[rf][0].z, L2E2, qs0[2]),
                        __builtin_fmaf(cur[rf][0].w, L2E2, qs0[3]),
                        __builtin_fmaf(cur[rf][1].x, L2E2, qs1[0]),
                        __builtin_fmaf(cur[rf][1].y, L2E2, qs1[1]),
                        __builtin_fmaf(cur[rf][1].z, L2E2, qs1[2]),
                        __builtin_fmaf(cur[rf][1].w, L2E2, qs1[3])};
                    union { unsigned short us[8]; bf16x8 v; } au;
#pragma unroll
                    for (int e = 0; e < 8; ++e) {
                        float e2 = fast_exp2(xin[e]);
                        float th = __builtin_fmaf(-2.0f, fast_rcp(e2 + 1.0f), 1.0f);
                        au.us[e] = f2b(th);
                    }
                    afr[rf] = au.v;
                }

                const int rslot = (kk * 4 + kq) ^ li;     // swizzled k-slot
#pragma unroll
                for (int c = 0; c < 16; ++c) {
                    const int o = (c >> 2) * 64 + li * 4 + (c & 3);
                    bf16x8 bfr = *(const bf16x8*)(wv_s + (size_t)o * 256 + rslot * 8);
                    acc[0][c] = __builtin_amdgcn_mfma_f32_16x16x32_bf16(afr[0], bfr, acc[0][c], 0, 0, 0);
                    acc[1][c] = __builtin_amdgcn_mfma_f32_16x16x32_bf16(afr[1], bfr, acc[1][c], 0, 0, 0);
                }
                if (kk < 7) {
#pragma unroll
                    for (int rf = 0; rf < 2; ++rf) {
                        cur[rf][0] = nxtA[rf][0]; cur[rf][1] = nxtA[rf][1];
                        nxtA[rf][0] = nxtB[rf][0]; nxtA[rf][1] = nxtB[rf][1];
                    }
                }
            }

            // prefetch next j-block's kk=0,1 BEFORE epilogue stores (loads
            // precede stores in the vmcnt FIFO; they overlap softmax+stores)
            {
                int njb = jb + 1, nit = it;
                if (njb == 2) { njb = 0; nit++; }
                if (nit < 4) {
                    const int nidx = xcd * 128 + nit * 32 + slot;
                    const int nb = nidx >> 9;
                    const int nrowbase = nb * M_ + (njb << 8);
                    LDK(nrowbase, 0, cur);
                    LDK(nrowbase, 1, nxtA);
                }
            }

            // ---- epilogue: softmax over 256 cols/row (bounded scores, no
            // max subtraction); per (row, chunk) one f32x4 nt store ----
            const size_t prow = (size_t)(b * N_ + i) * M_ + j0;
#pragma unroll
            for (int rf = 0; rf < 2; ++rf) {
#pragma unroll
                for (int v = 0; v < 4; ++v) {
                    float rsum = 0.f;
#pragma unroll
                    for (int c = 0; c < 16; ++c) {
                        float e = fast_exp2(acc[rf][c][v] * C);
                        acc[rf][c][v] = e;
                        rsum += e;
                    }
#pragma unroll
                    for (int mask = 1; mask < 16; mask <<= 1)
                        rsum += __shfl_xor(rsum, mask, 64);
                    const float inv = fast_rcp(rsum);
                    const int jl = wrow0 + rf * 16 + kq * 4 + v;
                    float* dst = attn + (prow + jl) * (size_t)H_ + li * 4;
#pragma unroll
                    for (int chunk = 0; chunk < 4; ++chunk) {
                        f32x4 s4 = (f32x4){acc[rf][chunk * 4][v] * inv,
                                           acc[rf][chunk * 4 + 1][v] * inv,
                                           acc[rf][chunk * 4 + 2][v] * inv,
                                           acc[rf][chunk * 4 + 3][v] * inv};
                        __builtin_nontemporal_store(s4, (f32x4*)(dst + chunk * 64));
                    }
                }
            }
        }
    }
#undef LDK
}

// ---------------------------------------------------------------------------
extern "C" void kernel_launch(void* const* d_in, const int* in_sizes, int n_in,
                              void* d_out, int out_size, void* d_ws, size_t ws_size,
                              hipStream_t stream) {
    (void)in_sizes; (void)n_in; (void)out_size; (void)ws_size;
    const float* queries = (const float*)d_in[0];
    const float* keys    = (const float*)d_in[1];
    const float* Wq = (const float*)d_in[3];
    const float* Wk = (const float*)d_in[4];
    const float* Wv = (const float*)d_in[5];
    const float* Wo = (const float*)d_in[6];

    float* out0 = (float*)d_out;                               // (B, n, H)
    float* attn = (float*)d_out + (size_t)B_ * N_ * H_;        // (B, n, m, H)

    float* ws  = (float*)d_ws;
    float* qp  = ws;                 // 262144 f
    float* kp  = ws + 262144;        // 262144 f
    float* vv  = ws + 524288;        // 262144 f
    float* ctx = ws + 786432;        // 262144 f

    proj3_kernel<<<dim3(128, 3), dim3(256), 0, stream>>>(queries, keys, Wq, Wk, Wv, qp, kp, vv);
    mh_attn_kernel<<<dim3(16, 16), dim3(256), 0, stream>>>(qp, kp, vv, ctx);
    proj_kernel<<<dim3(128), dim3(256), 0, stream>>>(ctx, Wo, out0);
    addattn_kernel<<<dim3(K2_BLOCKS), dim3(512), 0, stream>>>(qp, kp, Wv, attn);
}

// Round 6
// 220.847 us; speedup vs baseline: 4.5755x; 4.5755x over previous
//
#include <hip/hip_runtime.h>
#include <hip/hip_bf16.h>

#define B_  2
#define N_  512
#define M_  512
#define H_  256
#define NH_ 8
#define DH_ 32

typedef __attribute__((ext_vector_type(4))) float f32x4;
typedef __attribute__((ext_vector_type(8))) short bf16x8;

static __device__ __forceinline__ float fast_exp2(float x) { return __builtin_amdgcn_exp2f(x); }
static __device__ __forceinline__ float fast_rcp(float x)  { return __builtin_amdgcn_rcpf(x); }

// fp32 -> bf16 bits, round-to-nearest-even (inputs are finite)
static __device__ __forceinline__ unsigned short f2b(float f) {
    unsigned int u = __float_as_uint(f);
    u += 0x7fffu + ((u >> 16) & 1u);
    return (unsigned short)(u >> 16);
}

// ---------------------------------------------------------------------------
// K1: fused input projections. blockIdx.y selects {q@Wq, k@Wk, k@Wv}.
// ---------------------------------------------------------------------------
#define TM 8
__global__ __launch_bounds__(256) void proj3_kernel(const float* __restrict__ Q,
                                                    const float* __restrict__ K,
                                                    const float* __restrict__ Wq,
                                                    const float* __restrict__ Wk,
                                                    const float* __restrict__ Wv,
                                                    float* __restrict__ qp,
                                                    float* __restrict__ kp,
                                                    float* __restrict__ vv) {
    const int which = blockIdx.y;
    const float* X = (which == 0) ? Q : K;
    const float* W = (which == 0) ? Wq : (which == 1) ? Wk : Wv;
    float* Y = (which == 0) ? qp : (which == 1) ? kp : vv;

    __shared__ __align__(16) float xs[TM][H_];
    const int t = threadIdx.x;
    const int r0 = blockIdx.x * TM;
    for (int idx = t; idx < TM * H_; idx += 256)
        xs[idx >> 8][idx & 255] = X[(size_t)(r0 + (idx >> 8)) * H_ + (idx & 255)];
    __syncthreads();

    float acc[TM];
#pragma unroll
    for (int r = 0; r < TM; ++r) acc[r] = 0.f;

    const float* wrow = W + (size_t)t * H_;
    for (int k = 0; k < H_; k += 4) {
        float4 w4 = *(const float4*)(wrow + k);
#pragma unroll
        for (int r = 0; r < TM; ++r) {
            acc[r] += w4.x * xs[r][k] + w4.y * xs[r][k + 1] +
                      w4.z * xs[r][k + 2] + w4.w * xs[r][k + 3];
        }
    }
#pragma unroll
    for (int r = 0; r < TM; ++r) Y[(size_t)(r0 + r) * H_ + t] = acc[r];
}

// single-projection variant for the output GEMM
__global__ __launch_bounds__(256) void proj_kernel(const float* __restrict__ X,
                                                   const float* __restrict__ W,
                                                   float* __restrict__ Y) {
    __shared__ __align__(16) float xs[TM][H_];
    const int t = threadIdx.x;
    const int r0 = blockIdx.x * TM;
    for (int idx = t; idx < TM * H_; idx += 256)
        xs[idx >> 8][idx & 255] = X[(size_t)(r0 + (idx >> 8)) * H_ + (idx & 255)];
    __syncthreads();

    float acc[TM];
#pragma unroll
    for (int r = 0; r < TM; ++r) acc[r] = 0.f;

    const float* wrow = W + (size_t)t * H_;
    for (int k = 0; k < H_; k += 4) {
        float4 w4 = *(const float4*)(wrow + k);
#pragma unroll
        for (int r = 0; r < TM; ++r) {
            acc[r] += w4.x * xs[r][k] + w4.y * xs[r][k + 1] +
                      w4.z * xs[r][k + 2] + w4.w * xs[r][k + 3];
        }
    }
#pragma unroll
    for (int r = 0; r < TM; ++r) Y[(size_t)(r0 + r) * H_ + t] = acc[r];
}

// ---------------------------------------------------------------------------
// K3: multi-head dot-product attention (flash-style over j-tiles of 128)
// ---------------------------------------------------------------------------
__global__ __launch_bounds__(256) void mh_attn_kernel(const float* __restrict__ qp,
                                                      const float* __restrict__ kp,
                                                      const float* __restrict__ vv,
                                                      float* __restrict__ ctx) {
    __shared__ __align__(16) float ks[128][36];
    __shared__ __align__(16) float vs[128][36];
    const int t = threadIdx.x;
    const int bh = blockIdx.x;
    const int b = bh >> 3, head = bh & 7;
    const int i0 = blockIdx.y * 32;
    const int r = t >> 3, sub = t & 7;
    const int i = i0 + r;
    const float rs = 0.17677669529663687f;   // 1/sqrt(32)
    const float C = 1.4426950408889634f;     // log2(e)

    const float* qptr = qp + ((size_t)(b * N_ + i)) * H_ + head * DH_;
    float4 q[8];
#pragma unroll
    for (int d = 0; d < 8; ++d) q[d] = *(const float4*)(qptr + d * 4);

    float mrun = -1e30f, lrun = 0.f;
    float4 o[8];
#pragma unroll
    for (int d = 0; d < 8; ++d) o[d] = make_float4(0.f, 0.f, 0.f, 0.f);

    for (int jt = 0; jt < 4; ++jt) {
        __syncthreads();
#pragma unroll
        for (int cc = 0; cc < 4; ++cc) {
            int cIdx = t + cc * 256;
            int jr = cIdx >> 3, d4 = cIdx & 7;
            size_t gofs = ((size_t)(b * M_ + jt * 128 + jr)) * H_ + head * DH_ + d4 * 4;
            *(float4*)(&ks[jr][d4 * 4]) = *(const float4*)(kp + gofs);
            *(float4*)(&vs[jr][d4 * 4]) = *(const float4*)(vv + gofs);
        }
        __syncthreads();

        float s16[16];
#pragma unroll
        for (int jj = 0; jj < 16; ++jj) {
            const float* kr = ks[sub + jj * 8];
            float a = 0.f;
#pragma unroll
            for (int d = 0; d < 8; ++d) {
                float4 kv = *(const float4*)(kr + d * 4);
                a += q[d].x * kv.x + q[d].y * kv.y + q[d].z * kv.z + q[d].w * kv.w;
            }
            s16[jj] = a * rs;
        }
        float tm = s16[0];
#pragma unroll
        for (int jj = 1; jj < 16; ++jj) tm = fmaxf(tm, s16[jj]);
        float mnew = fmaxf(mrun, tm);
        float corr = fast_exp2((mrun - mnew) * C);
        lrun *= corr;
#pragma unroll
        for (int d = 0; d < 8; ++d) {
            o[d].x *= corr; o[d].y *= corr; o[d].z *= corr; o[d].w *= corr;
        }
        mrun = mnew;
#pragma unroll
        for (int jj = 0; jj < 16; ++jj) {
            float p = fast_exp2((s16[jj] - mrun) * C);
            lrun += p;
            const float* vr = vs[sub + jj * 8];
#pragma unroll
            for (int d = 0; d < 8; ++d) {
                float4 vx = *(const float4*)(vr + d * 4);
                o[d].x = __builtin_fmaf(p, vx.x, o[d].x);
                o[d].y = __builtin_fmaf(p, vx.y, o[d].y);
                o[d].z = __builtin_fmaf(p, vx.z, o[d].z);
                o[d].w = __builtin_fmaf(p, vx.w, o[d].w);
            }
        }
    }

#pragma unroll
    for (int mask = 1; mask < 8; mask <<= 1) {
        float om = __shfl_xor(mrun, mask, 64);
        float ol = __shfl_xor(lrun, mask, 64);
        float Mx = fmaxf(mrun, om);
        float fa = fast_exp2((mrun - Mx) * C);
        float fb = fast_exp2((om - Mx) * C);
        lrun = lrun * fa + ol * fb;
#pragma unroll
        for (int d = 0; d < 8; ++d) {
            float ox = __shfl_xor(o[d].x, mask, 64);
            float oy = __shfl_xor(o[d].y, mask, 64);
            float oz = __shfl_xor(o[d].z, mask, 64);
            float ow = __shfl_xor(o[d].w, mask, 64);
            o[d].x = o[d].x * fa + ox * fb;
            o[d].y = o[d].y * fa + oy * fb;
            o[d].z = o[d].z * fa + oz * fb;
            o[d].w = o[d].w * fa + ow * fb;
        }
        mrun = Mx;
    }
    float inv = fast_rcp(lrun);
    float4 r4 = make_float4(0.f, 0.f, 0.f, 0.f);
#pragma unroll
    for (int d = 0; d < 8; ++d) if (sub == d) r4 = o[d];
    r4.x *= inv; r4.y *= inv; r4.z *= inv; r4.w *= inv;
    *(float4*)(ctx + ((size_t)(b * N_ + i)) * H_ + head * DH_ + sub * 4) = r4;
}

// ---------------------------------------------------------------------------
// K2: additive-attention branch — R0 structure RESTORED.
// Per-tile barriers keep the 8 waves lockstep: each tile is a [read+compute]
// phase (store queue drained -> 512-KB hot kp set stays L2-resident across
// the 128 blocks sharing it) followed by a store-drain phase at the next
// barrier. Removing these barriers (R3-R5) destroyed kp L2 reuse
// (FETCH 1.08 GB) and cost 2.5-4x. Scalar dword nt stores: each 16-lane
// group writes one full 64B line per instruction.
// Only delta vs R0: no-max softmax (scores bounded by ||Wv row||_1 ~ 4).
// ---------------------------------------------------------------------------
#define BM2 256
#define TILES_TOTAL 2048
#define K2_BLOCKS 256

__global__ __launch_bounds__(512, 2) void addattn_kernel(const float* __restrict__ qp,
                                                         const float* __restrict__ kp,
                                                         const float* __restrict__ Wv,
                                                         float* __restrict__ attn) {
    __shared__ __align__(16) unsigned short wv_s[H_ * H_];  // 128 KB swizzled bf16
    __shared__ __align__(16) float qrow[H_];                // 1 KB

    const int t = threadIdx.x;
    const int lane = t & 63;
    const int w = t >> 6;        // wave 0..7
    const int li = lane & 15;
    const int kq = lane >> 4;    // 0..3
    const int wrow0 = w * 32;
    const float C = 1.4426950408889634f;
    const float L2E2 = 2.885390081777927f;   // 2*log2(e)

    // ---- stage Wv as bf16 with 16B-slot XOR swizzle (key = o&15) ----
#pragma unroll
    for (int it = 0; it < 16; ++it) {
        int sIdx = t + it * 512;          // 16B-slot index 0..8191
        int o = sIdx >> 5;
        int slot = sIdx & 31;
        const float* src = Wv + (size_t)o * H_ + slot * 8;
        float4 a = *(const float4*)(src);
        float4 bq = *(const float4*)(src + 4);
        union { unsigned short us[8]; uint4 v; } pk;
        pk.us[0] = f2b(a.x);  pk.us[1] = f2b(a.y);  pk.us[2] = f2b(a.z);  pk.us[3] = f2b(a.w);
        pk.us[4] = f2b(bq.x); pk.us[5] = f2b(bq.y); pk.us[6] = f2b(bq.z); pk.us[7] = f2b(bq.w);
        int dslot = slot ^ (o & 15);
        *(uint4*)(wv_s + (size_t)o * 256 + dslot * 8) = pk.v;
    }

    int tile = blockIdx.x;

    // preload first tile's kp slices (kk = 0)
    float4 cur[2][2];
    {
        const int b = tile >> 10;
        const int j0 = (tile & 1) * BM2;
#pragma unroll
        for (int rf = 0; rf < 2; ++rf) {
            const int jl = wrow0 + rf * 16 + li;
            const float* kr = kp + ((size_t)(b * M_ + j0 + jl)) * H_ + kq * 8;
            cur[rf][0] = *(const float4*)(kr);
            cur[rf][1] = *(const float4*)(kr + 4);
        }
    }

    for (; tile < TILES_TOTAL; tile += K2_BLOCKS) {
        const int b = tile >> 10;                 // tile / 1024
        const int i = (tile >> 1) & (N_ - 1);
        const int j0 = (tile & 1) * BM2;

        __syncthreads();   // prior tile done with qrow; store queue drains here
        if (t < 64) *(float4*)(qrow + t * 4) = *(const float4*)(qp + ((size_t)(b * N_ + i)) * H_ + t * 4);
        __syncthreads();   // qrow (and, on 1st iter, wv_s) visible

        f32x4 acc[2][16];
#pragma unroll
        for (int rf = 0; rf < 2; ++rf)
#pragma unroll
            for (int c = 0; c < 16; ++c) acc[rf][c] = (f32x4){0.f, 0.f, 0.f, 0.f};

#pragma unroll
        for (int kk = 0; kk < 8; ++kk) {
            float4 nxt[2][2];
            if (kk < 7) {
#pragma unroll
                for (int rf = 0; rf < 2; ++rf) {
                    const int jl = wrow0 + rf * 16 + li;
                    const float* kr = kp + ((size_t)(b * M_ + j0 + jl)) * H_ + (kk + 1) * 32 + kq * 8;
                    nxt[rf][0] = *(const float4*)(kr);
                    nxt[rf][1] = *(const float4*)(kr + 4);
                }
            }
            float4 q0 = *(const float4*)(qrow + kk * 32 + kq * 8);
            float4 q1 = *(const float4*)(qrow + kk * 32 + kq * 8 + 4);

            bf16x8 afr[2];
#pragma unroll
            for (int rf = 0; rf < 2; ++rf) {
                float xin[8] = {cur[rf][0].x + q0.x, cur[rf][0].y + q0.y,
                                cur[rf][0].z + q0.z, cur[rf][0].w + q0.w,
                                cur[rf][1].x + q1.x, cur[rf][1].y + q1.y,
                                cur[rf][1].z + q1.z, cur[rf][1].w + q1.w};
                union { unsigned short us[8]; bf16x8 v; } au;
#pragma unroll
                for (int e = 0; e < 8; ++e) {
                    float e2 = fast_exp2(xin[e] * L2E2);
                    float th = __builtin_fmaf(-2.0f, fast_rcp(e2 + 1.0f), 1.0f);
                    au.us[e] = f2b(th);
                }
                afr[rf] = au.v;
            }

#pragma unroll
            for (int c = 0; c < 16; ++c) {
                const int o = c * 16 + li;
                const int slot = (kk * 4 + kq) ^ (o & 15);
                bf16x8 bfr = *(const bf16x8*)(wv_s + (size_t)o * 256 + slot * 8);
                acc[0][c] = __builtin_amdgcn_mfma_f32_16x16x32_bf16(afr[0], bfr, acc[0][c], 0, 0, 0);
                acc[1][c] = __builtin_amdgcn_mfma_f32_16x16x32_bf16(afr[1], bfr, acc[1][c], 0, 0, 0);
            }
            if (kk < 7) {
#pragma unroll
                for (int rf = 0; rf < 2; ++rf) { cur[rf][0] = nxt[rf][0]; cur[rf][1] = nxt[rf][1]; }
            }
        }

        // prefetch next tile's kp (kk=0) BEFORE the epilogue stores
        if (tile + K2_BLOCKS < TILES_TOTAL) {
            const int nt = tile + K2_BLOCKS;
            const int nb = nt >> 10;
            const int nj0 = (nt & 1) * BM2;
#pragma unroll
            for (int rf = 0; rf < 2; ++rf) {
                const int jl = wrow0 + rf * 16 + li;
                const float* kr = kp + ((size_t)(nb * M_ + nj0 + jl)) * H_ + kq * 8;
                cur[rf][0] = *(const float4*)(kr);
                cur[rf][1] = *(const float4*)(kr + 4);
            }
        }

        // ---- epilogue: softmax over the 256 cols of each row (bounded
        // scores -> no max subtraction), scalar dword nt stores (full 64B
        // line per 16-lane group per instruction) ----
        const size_t prow = (size_t)tile * BM2;
#pragma unroll
        for (int rf = 0; rf < 2; ++rf) {
#pragma unroll
            for (int v = 0; v < 4; ++v) {
                float p[16];
                float rsum = 0.f;
#pragma unroll
                for (int c = 0; c < 16; ++c) {
                    p[c] = fast_exp2(acc[rf][c][v] * C);
                    rsum += p[c];
                }
#pragma unroll
                for (int mask = 1; mask < 16; mask <<= 1)
                    rsum += __shfl_xor(rsum, mask, 64);
                const float inv = fast_rcp(rsum);
                const int jl = wrow0 + rf * 16 + kq * 4 + v;
                float* dst = attn + (prow + jl) * (size_t)H_ + li;
#pragma unroll
                for (int c = 0; c < 16; ++c)
                    __builtin_nontemporal_store(p[c] * inv, dst + c * 16);
            }
        }
    }
}

// ---------------------------------------------------------------------------
extern "C" void kernel_launch(void* const* d_in, const int* in_sizes, int n_in,
                              void* d_out, int out_size, void* d_ws, size_t ws_size,
                              hipStream_t stream) {
    (void)in_sizes; (void)n_in; (void)out_size; (void)ws_size;
    const float* queries = (const float*)d_in[0];
    const float* keys    = (const float*)d_in[1];
    const float* Wq = (const float*)d_in[3];
    const float* Wk = (const float*)d_in[4];
    const float* Wv = (const float*)d_in[5];
    const float* Wo = (const float*)d_in[6];

    float* out0 = (float*)d_out;                               // (B, n, H)
    float* attn = (float*)d_out + (size_t)B_ * N_ * H_;        // (B, n, m, H)

    float* ws  = (float*)d_ws;
    float* qp  = ws;                 // 262144 f
    float* kp  = ws + 262144;        // 262144 f
    float* vv  = ws + 524288;        // 262144 f
    float* ctx = ws + 786432;        // 262144 f

    proj3_kernel<<<dim3(128, 3), dim3(256), 0, stream>>>(queries, keys, Wq, Wk, Wv, qp, kp, vv);
    mh_attn_kernel<<<dim3(16, 16), dim3(256), 0, stream>>>(qp, kp, vv, ctx);
    proj_kernel<<<dim3(128), dim3(256), 0, stream>>>(ctx, Wo, out0);
    addattn_kernel<<<dim3(K2_BLOCKS), dim3(512), 0, stream>>>(qp, kp, Wv, attn);
}